// Round 1
// baseline (471.156 us; speedup 1.0000x reference)
//
#include <hip/hip_runtime.h>
#include <math.h>

// MaxMarginLoss: B=4,S=512,D=512,V=32000, gamma=0.5, eps=1e-12
// score[r,v] = (out_norm[r] - tgt_emb[r]) . voc_norm[v]  -> argmax_v (first-idx ties)
// loss = mean over non-pad rows of max(gamma + cos(out,voc[jmax]) - cos(out,voc[tgt]), 0)
//
// R13 = R12 with the GEMM inner engine swapped to MX-scaled fp8:
//  - mfma_scale_f32_16x16x128_f8f6f4 (K=128/instr, 2x rate of non-scaled fp8,
//    which runs at bf16 rate). Uniform E8M0 scale 127 (=1.0) => numerically
//    identical scores; coarse-argmax + fp32 rescue contract unchanged.
//  - 4x fewer MFMA instrs, 2x fewer ds_read instrs; staging/barriers/epilogue
//    identical to R12. Precedent: learn_hip m145->m148, 995->1628 TF at this
//    same 128^2 structure.

#define Bb 4
#define Ss 512
#define Dd 512
#define Vv 32000
#define ROWS (Bb * Ss)          // 2048
#define NTILE_M (ROWS / 128)    // 16
#define NTILE_N (Vv / 128)      // 250
#define VOC_BLOCKS (Vv / 4)     // 8000
#define MARGIN 0.5f

typedef __attribute__((ext_vector_type(4))) float f32x4;
typedef __attribute__((ext_vector_type(8))) int i32x8;

__device__ __forceinline__ float waveReduceSum(float x) {
#pragma unroll
  for (int m = 32; m >= 1; m >>= 1) x += __shfl_xor(x, m, 64);
  return x;
}

__device__ __forceinline__ float waveReduceMax(float x) {
#pragma unroll
  for (int m = 32; m >= 1; m >>= 1) x = fmaxf(x, __shfl_xor(x, m, 64));
  return x;
}

// float -> fp8 e4m3 (OCP on gfx950), low byte of packed convert
__device__ __forceinline__ unsigned char f2e4m3(float f) {
  int p = __builtin_amdgcn_cvt_pk_fp8_f32(f, f, 0, false);
  return (unsigned char)(p & 0xff);
}

__device__ __forceinline__ void async_ld16(const void* g, void* l) {
  __builtin_amdgcn_global_load_lds((const __attribute__((address_space(1))) void*)g,
                                   (__attribute__((address_space(3))) void*)l, 16, 0, 0);
}

// K1: fused prep. blocks [0,8000): 4 vocab rows -> e8 (normalized, fp8) + inv_norm.
//     blocks [8000,10048): ONE preds row -> o_rows(f32), u8(fp8), cos_tgt(f32).
__global__ __launch_bounds__(256) void prep_all(
    const float* __restrict__ preds, const float* __restrict__ emb,
    const int* __restrict__ target,
    float* __restrict__ o_rows, unsigned char* __restrict__ u8,
    float* __restrict__ cos_tgt, unsigned char* __restrict__ e8,
    float* __restrict__ inv_norm) {
  int tid = threadIdx.x;
  int wave = tid >> 6, lane = tid & 63;
  if (blockIdx.x < VOC_BLOCKS) {
    int v = blockIdx.x * 4 + wave;
    const float* e = emb + (size_t)v * Dd;
    float4 x0 = *(const float4*)(e + lane * 8);
    float4 x1 = *(const float4*)(e + lane * 8 + 4);
    float ss = x0.x * x0.x + x0.y * x0.y + x0.z * x0.z + x0.w * x0.w +
               x1.x * x1.x + x1.y * x1.y + x1.z * x1.z + x1.w * x1.w;
    ss = waveReduceSum(ss);
    float inv = 1.0f / fmaxf(sqrtf(ss), 1e-12f);
    int lo = __builtin_amdgcn_cvt_pk_fp8_f32(x0.x * inv, x0.y * inv, 0, false);
    lo = __builtin_amdgcn_cvt_pk_fp8_f32(x0.z * inv, x0.w * inv, lo, true);
    int hi = __builtin_amdgcn_cvt_pk_fp8_f32(x1.x * inv, x1.y * inv, 0, false);
    hi = __builtin_amdgcn_cvt_pk_fp8_f32(x1.z * inv, x1.w * inv, hi, true);
    int2 pk = make_int2(lo, hi);
    *(int2*)(e8 + (size_t)v * Dd + lane * 8) = pk;
    if (lane == 0) inv_norm[v] = inv;
  } else {
    int row = blockIdx.x - VOC_BLOCKS;
    int b = row >> 9, s = row & (Ss - 1);
    const float* p = preds + (size_t)b * Dd * Ss + s;
    float x0 = p[(size_t)tid * Ss];
    float x1 = p[(size_t)(tid + 256) * Ss];
    __shared__ float red[12];
    float ss = waveReduceSum(x0 * x0 + x1 * x1);
    if (lane == 0) red[wave] = ss;
    __syncthreads();
    float inv = 1.0f / fmaxf(sqrtf(red[0] + red[1] + red[2] + red[3]), 1e-12f);
    float o0 = x0 * inv, o1 = x1 * inv;
    o_rows[(size_t)row * Dd + tid] = o0;
    o_rows[(size_t)row * Dd + tid + 256] = o1;
    int t = target[row];
    const float* et = emb + (size_t)t * Dd;
    float e0 = et[tid], e1 = et[tid + 256];
    u8[(size_t)row * Dd + tid] = f2e4m3(o0 - e0);
    u8[(size_t)row * Dd + tid + 256] = f2e4m3(o1 - e1);
    float ss2 = waveReduceSum(e0 * e0 + e1 * e1);
    float dt = waveReduceSum(o0 * e0 + o1 * e1);
    if (lane == 0) { red[4 + wave] = ss2; red[8 + wave] = dt; }
    __syncthreads();
    if (tid == 0) {
      float n2 = red[4] + red[5] + red[6] + red[7];
      float dd = red[8] + red[9] + red[10] + red[11];
      cos_tgt[row] = dd * (1.0f / fmaxf(sqrtf(n2), 1e-12f));
    }
  }
}

// K2: 128x128-tile MX-fp8 MFMA GEMM (B^T), BK=128 bytes, XOR-8 bank swizzle,
// XCD strips, + coarse per-tile argmax epilogue. Partials row-major.
// One mfma_scale K=128 per (mi,ni) per K-step; uniform scale = 1.0 (E8M0 127).
__global__ __launch_bounds__(256, 4) void gemm_argmax(
    const unsigned char* __restrict__ u8, const unsigned char* __restrict__ e8,
    float* __restrict__ part_s, int* __restrict__ part_i) {
  __shared__ unsigned char sA[128 * 128];  // 16 KB
  __shared__ unsigned char sB[128 * 128];  // 16 KB
  int bid = blockIdx.x;
  int g = (bid & 7) * 500 + (bid >> 3);
  int tm = g & 15, tn = g >> 4;
  int tid = threadIdx.x;
  int w = tid >> 6, lane = tid & 63;
  int wm = w >> 1, wn = w & 1;

  // staging: glds dest = wave-base + lane*16 -> row = lane>>3, chunk = lane&7.
  // lane sources GLOBAL 16B chunk (lane&7)^((lane>>3)&7): phys chunk (lane&7)
  // of row r holds logical chunk (lane&7)^(r&7).
  int srow = w * 8 + (lane >> 3);
  int schunk = (lane & 7) ^ ((lane >> 3) & 7);
  const unsigned char* gA = u8 + (size_t)(tm * 128 + srow) * Dd + schunk * 16;
  const unsigned char* gB = e8 + (size_t)(tn * 128 + srow) * Dd + schunk * 16;

  // fragment read (mfma_scale 16x16x128 fp8: row=lane&15, k=(lane>>4)*32+j):
  // lane's 32 logical bytes = logical chunks {2q, 2q+1}; phys = logical^(fr&7).
  int fr = lane & 15;
  int q = lane >> 4;
  int flow = fr & 7;
  int pc0 = (2 * q) ^ flow;        // phys chunk of logical chunk 2q
  int pc1 = (2 * q + 1) ^ flow;    // phys chunk of logical chunk 2q+1

  f32x4 acc[4][4];
  f32x4 z = {0.f, 0.f, 0.f, 0.f};
#pragma unroll
  for (int mi = 0; mi < 4; ++mi)
#pragma unroll
    for (int ni = 0; ni < 4; ++ni) acc[mi][ni] = z;

  for (int kk = 0; kk < 4; ++kk) {  // 4 K-steps of 128 bytes
    __syncthreads();  // previous compute done before overwrite
    {
      const unsigned char* ga = gA + kk * 128;
      const unsigned char* gb = gB + kk * 128;
#pragma unroll
      for (int i = 0; i < 4; ++i) {
        async_ld16(ga + (size_t)(i * 32) * Dd, &sA[(w * 8 + i * 32) * 128]);
        async_ld16(gb + (size_t)(i * 32) * Dd, &sB[(w * 8 + i * 32) * 128]);
      }
    }
    __syncthreads();  // staging visible (vmcnt drained by barrier)

    i32x8 af[4], bg[4];
#pragma unroll
    for (int mi = 0; mi < 4; ++mi) {
      const unsigned char* pa = sA + (wm * 64 + mi * 16 + fr) * 128;
      int4 lo = *(const int4*)(pa + pc0 * 16);
      int4 hi = *(const int4*)(pa + pc1 * 16);
      af[mi][0] = lo.x; af[mi][1] = lo.y; af[mi][2] = lo.z; af[mi][3] = lo.w;
      af[mi][4] = hi.x; af[mi][5] = hi.y; af[mi][6] = hi.z; af[mi][7] = hi.w;
    }
#pragma unroll
    for (int ni = 0; ni < 4; ++ni) {
      const unsigned char* pb = sB + (wn * 64 + ni * 16 + fr) * 128;
      int4 lo = *(const int4*)(pb + pc0 * 16);
      int4 hi = *(const int4*)(pb + pc1 * 16);
      bg[ni][0] = lo.x; bg[ni][1] = lo.y; bg[ni][2] = lo.z; bg[ni][3] = lo.w;
      bg[ni][4] = hi.x; bg[ni][5] = hi.y; bg[ni][6] = hi.z; bg[ni][7] = hi.w;
    }
#pragma unroll
    for (int mi = 0; mi < 4; ++mi)
#pragma unroll
      for (int ni = 0; ni < 4; ++ni)
        acc[mi][ni] = __builtin_amdgcn_mfma_scale_f32_16x16x128_f8f6f4(
            af[mi], bg[ni], acc[mi][ni], 0, 0,  // cbsz=fp8, blgp=fp8
            0, 0x7F7F7F7F,                      // opsel_a, scale_a = 1.0 (E8M0)
            0, 0x7F7F7F7F);                     // opsel_b, scale_b = 1.0
  }

  // ---- coarse argmax epilogue ----
  // C layout: col = lane&15, row = (lane>>4)*4 + reg
  float bs[4][4];
  int bc[4][4];
  int col0 = tn * 128 + wn * 64 + (lane & 15);
#pragma unroll
  for (int mi = 0; mi < 4; ++mi) {
#pragma unroll
    for (int j = 0; j < 4; ++j) { bs[mi][j] = acc[mi][0][j]; bc[mi][j] = col0; }
#pragma unroll
    for (int ni = 1; ni < 4; ++ni) {
      int c = col0 + ni * 16;
#pragma unroll
      for (int j = 0; j < 4; ++j) {
        float v = acc[mi][ni][j];
        if (v > bs[mi][j]) { bs[mi][j] = v; bc[mi][j] = c; }
      }
    }
  }
#pragma unroll
  for (int m = 1; m < 16; m <<= 1) {
#pragma unroll
    for (int mi = 0; mi < 4; ++mi)
#pragma unroll
      for (int j = 0; j < 4; ++j) {
        float os = __shfl_xor(bs[mi][j], m, 64);
        int oc = __shfl_xor(bc[mi][j], m, 64);
        if (os > bs[mi][j] || (os == bs[mi][j] && oc < bc[mi][j])) {
          bs[mi][j] = os;
          bc[mi][j] = oc;
        }
      }
  }
  __syncthreads();  // done reading sA/sB; reuse as merge scratch
  float* sEs = (float*)sA;          // [2][128]
  int* sEc = (int*)sA + 256;        // [2][128]
  if ((lane & 15) == 0) {
    int qq = lane >> 4;
#pragma unroll
    for (int mi = 0; mi < 4; ++mi)
#pragma unroll
      for (int j = 0; j < 4; ++j) {
        int rloc = wm * 64 + mi * 16 + qq * 4 + j;
        sEs[wn * 128 + rloc] = bs[mi][j];
        sEc[wn * 128 + rloc] = bc[mi][j];
      }
  }
  __syncthreads();
  if (tid < 128) {
    float s0 = sEs[tid], s1 = sEs[128 + tid];
    int c0 = sEc[tid], c1 = sEc[128 + tid];
    if (s1 > s0 || (s1 == s0 && c1 < c0)) { s0 = s1; c0 = c1; }
    // row-major partials: coalesced reads in row_final
    part_s[(size_t)(tm * 128 + tid) * 256 + tn] = s0;
    part_i[(size_t)(tm * 128 + tid) * 256 + tn] = c0;
  }
}

// K3: parallel fp32 rescue. One block per row: coalesced partial read,
// block max, LDS candidate list (cols unique per tile), 4 waves rescore
// candidates cooperatively with exact fp32 dots, merge, hinge.
__global__ __launch_bounds__(256) void row_final(
    const float* __restrict__ o_rows, const float* __restrict__ emb,
    const float* __restrict__ inv_norm, const float* __restrict__ cos_tgt,
    const int* __restrict__ target, const int* __restrict__ pad_id,
    const float* __restrict__ part_s, const int* __restrict__ part_i,
    float* __restrict__ diffs) {
  int row = blockIdx.x;
  int tid = threadIdx.x;
  int w = tid >> 6, lane = tid & 63;
  __shared__ float sMax[4];
  __shared__ int sCand[256];
  __shared__ int sCnt;
  __shared__ float sBs[4], sBp[4];
  __shared__ int sBc[4];
  // phase 1: block max over the 250 tile partials (coalesced)
  float v = (tid < NTILE_N) ? part_s[(size_t)row * 256 + tid] : -INFINITY;
  float wmax = waveReduceMax(v);
  if (lane == 0) sMax[w] = wmax;
  if (tid == 0) sCnt = 0;
  __syncthreads();
  float thr = fmaxf(fmaxf(sMax[0], sMax[1]), fmaxf(sMax[2], sMax[3])) - MARGIN;
  // phase 2: candidate list (tile-winner cols are unique across tiles)
  if (tid < NTILE_N && v >= thr) {
    int idx = atomicAdd(&sCnt, 1);
    sCand[idx] = part_i[(size_t)row * 256 + tid];
  }
  __syncthreads();
  int n = sCnt;  // >= 1 (the max tile always qualifies)
  // per-lane row data
  int tgt = target[row];
  const float* o = o_rows + (size_t)row * Dd;
  const float* et = emb + (size_t)tgt * Dd;
  float4 oa = *(const float4*)(o + lane * 8);
  float4 ob = *(const float4*)(o + lane * 8 + 4);
  float4 ta = *(const float4*)(et + lane * 8);
  float4 tb = *(const float4*)(et + lane * 8 + 4);
  // phase 3: waves round-robin candidates
  float bscore = -INFINITY, bpo = 0.f;
  int bcol = 0x7fffffff;
  for (int i = w; i < n; i += 4) {
    int c = sCand[i];
    const float* ec = emb + (size_t)c * Dd;
    float4 ea = *(const float4*)(ec + lane * 8);
    float4 eb = *(const float4*)(ec + lane * 8 + 4);
    float po = oa.x * ea.x + oa.y * ea.y + oa.z * ea.z + oa.w * ea.w +
               ob.x * eb.x + ob.y * eb.y + ob.z * eb.z + ob.w * eb.w;
    float pt = ta.x * ea.x + ta.y * ea.y + ta.z * ea.z + ta.w * ea.w +
               tb.x * eb.x + tb.y * eb.y + tb.z * eb.z + tb.w * eb.w;
    po = waveReduceSum(po);
    pt = waveReduceSum(pt);
    float sc = (po - pt) * inv_norm[c];
    if (sc > bscore || (sc == bscore && c < bcol)) {
      bscore = sc;
      bcol = c;
      bpo = po;
    }
  }
  if (lane == 0) { sBs[w] = bscore; sBc[w] = bcol; sBp[w] = bpo; }
  __syncthreads();
  if (tid == 0) {
    float s = sBs[0], p = sBp[0];
    int c = sBc[0];
#pragma unroll
    for (int i = 1; i < 4; ++i)
      if (sBs[i] > s || (sBs[i] == s && sBc[i] < c)) { s = sBs[i]; c = sBc[i]; p = sBp[i]; }
    float cmax = p * inv_norm[c];
    float df = fmaxf(0.5f + cmax - cos_tgt[row], 0.0f);
    diffs[row] = (tgt != pad_id[0]) ? df : 0.0f;
  }
}

// F: masked mean.
__global__ __launch_bounds__(256) void reduce_final(
    const float* __restrict__ diffs, const int* __restrict__ target,
    const int* __restrict__ pad_id, float* __restrict__ out) {
  int tid = threadIdx.x;
  int pid = pad_id[0];
  float s = 0.f, c = 0.f;
  for (int i = tid; i < ROWS; i += 256) {
    s += diffs[i];
    c += (target[i] != pid) ? 1.0f : 0.0f;
  }
  s = waveReduceSum(s);
  c = waveReduceSum(c);
  __shared__ float rs[4], rc[4];
  int wave = tid >> 6, lane = tid & 63;
  if (lane == 0) { rs[wave] = s; rc[wave] = c; }
  __syncthreads();
  if (tid == 0) out[0] = (rs[0] + rs[1] + rs[2] + rs[3]) / (rc[0] + rc[1] + rc[2] + rc[3]);
}

extern "C" void kernel_launch(void* const* d_in, const int* in_sizes, int n_in,
                              void* d_out, int out_size, void* d_ws, size_t ws_size,
                              hipStream_t stream) {
  const float* preds = (const float*)d_in[0];
  const float* emb = (const float*)d_in[1];
  const int* target = (const int*)d_in[2];
  const int* pad_id = (const int*)d_in[3];
  char* ws = (char*)d_ws;
  // ws layout (bytes), total ~26 MB
  float* o_rows = (float*)ws;                          // 2048*512*4 = 4,194,304
  unsigned char* u8 = (unsigned char*)(ws + 4194304);  // 2048*512   = 1,048,576
  unsigned char* e8 = (unsigned char*)(ws + 5242880);  // 32000*512  = 16,384,000
  float* inv_norm = (float*)(ws + 21626880);           // 32000*4    = 128,000
  float* cos_tgt = (float*)(ws + 21754880);            // 2048*4     = 8,192
  float* part_s = (float*)(ws + 21763072);             // 2048*256*4 = 2,097,152
  int* part_i = (int*)(ws + 23860224);                 // 2048*256*4 = 2,097,152
  float* diffs = (float*)(ws + 25957376);              // 2048*4

  prep_all<<<VOC_BLOCKS + ROWS, 256, 0, stream>>>(preds, emb, target, o_rows, u8,
                                                  cos_tgt, e8, inv_norm);
  gemm_argmax<<<NTILE_M * NTILE_N, 256, 0, stream>>>(u8, e8, part_s, part_i);
  row_final<<<ROWS, 256, 0, stream>>>(o_rows, emb, inv_norm, cos_tgt, target,
                                      pad_id, part_s, part_i, diffs);
  reduce_final<<<1, 256, 0, stream>>>(diffs, target, pad_id, (float*)d_out);
}

// Round 2
// 376.095 us; speedup vs baseline: 1.2528x; 1.2528x over previous
//
#include <hip/hip_runtime.h>
#include <math.h>

// MaxMarginLoss: B=4,S=512,D=512,V=32000, gamma=0.5, eps=1e-12
// score[r,v] = (out_norm[r] - tgt_emb[r]) . voc_norm[v]  -> argmax_v (first-idx ties)
// loss = mean over non-pad rows of max(gamma + cos(out,voc[jmax]) - cos(out,voc[tgt]), 0)
//
// R14 = R13 (MX-scaled fp8 GEMM, numerically verified) with the spill fixed:
//  - R13 spilled acc to scratch (VGPR=64 under (256,4) cap; 1.5 GB/dispatch
//    scratch traffic). Fix: 2 rotating B fragments instead of bg[4], direct
//    32B i32x8 fragment loads (no int4 repack temps), launch_bounds (256,3)
//    -> VGPR cap ~168, no spill.
//  - 32B load trick: lane's two swizzled 16B chunks (2q)^flow, (2q+1)^flow are
//    the SAME aligned 32B block, half-swapped when flow&1. A and B use the
//    same flow per lane -> identical k-permutation on both operands -> dot
//    product unchanged (and stays within the lane's 32-wide MX scale block).

#define Bb 4
#define Ss 512
#define Dd 512
#define Vv 32000
#define ROWS (Bb * Ss)          // 2048
#define NTILE_M (ROWS / 128)    // 16
#define NTILE_N (Vv / 128)      // 250
#define VOC_BLOCKS (Vv / 4)     // 8000
#define MARGIN 0.5f

typedef __attribute__((ext_vector_type(4))) float f32x4;
typedef __attribute__((ext_vector_type(8))) int i32x8;

__device__ __forceinline__ float waveReduceSum(float x) {
#pragma unroll
  for (int m = 32; m >= 1; m >>= 1) x += __shfl_xor(x, m, 64);
  return x;
}

__device__ __forceinline__ float waveReduceMax(float x) {
#pragma unroll
  for (int m = 32; m >= 1; m >>= 1) x = fmaxf(x, __shfl_xor(x, m, 64));
  return x;
}

// float -> fp8 e4m3 (OCP on gfx950), low byte of packed convert
__device__ __forceinline__ unsigned char f2e4m3(float f) {
  int p = __builtin_amdgcn_cvt_pk_fp8_f32(f, f, 0, false);
  return (unsigned char)(p & 0xff);
}

__device__ __forceinline__ void async_ld16(const void* g, void* l) {
  __builtin_amdgcn_global_load_lds((const __attribute__((address_space(1))) void*)g,
                                   (__attribute__((address_space(3))) void*)l, 16, 0, 0);
}

// K1: fused prep. blocks [0,8000): 4 vocab rows -> e8 (normalized, fp8) + inv_norm.
//     blocks [8000,10048): ONE preds row -> o_rows(f32), u8(fp8), cos_tgt(f32).
__global__ __launch_bounds__(256) void prep_all(
    const float* __restrict__ preds, const float* __restrict__ emb,
    const int* __restrict__ target,
    float* __restrict__ o_rows, unsigned char* __restrict__ u8,
    float* __restrict__ cos_tgt, unsigned char* __restrict__ e8,
    float* __restrict__ inv_norm) {
  int tid = threadIdx.x;
  int wave = tid >> 6, lane = tid & 63;
  if (blockIdx.x < VOC_BLOCKS) {
    int v = blockIdx.x * 4 + wave;
    const float* e = emb + (size_t)v * Dd;
    float4 x0 = *(const float4*)(e + lane * 8);
    float4 x1 = *(const float4*)(e + lane * 8 + 4);
    float ss = x0.x * x0.x + x0.y * x0.y + x0.z * x0.z + x0.w * x0.w +
               x1.x * x1.x + x1.y * x1.y + x1.z * x1.z + x1.w * x1.w;
    ss = waveReduceSum(ss);
    float inv = 1.0f / fmaxf(sqrtf(ss), 1e-12f);
    int lo = __builtin_amdgcn_cvt_pk_fp8_f32(x0.x * inv, x0.y * inv, 0, false);
    lo = __builtin_amdgcn_cvt_pk_fp8_f32(x0.z * inv, x0.w * inv, lo, true);
    int hi = __builtin_amdgcn_cvt_pk_fp8_f32(x1.x * inv, x1.y * inv, 0, false);
    hi = __builtin_amdgcn_cvt_pk_fp8_f32(x1.z * inv, x1.w * inv, hi, true);
    int2 pk = make_int2(lo, hi);
    *(int2*)(e8 + (size_t)v * Dd + lane * 8) = pk;
    if (lane == 0) inv_norm[v] = inv;
  } else {
    int row = blockIdx.x - VOC_BLOCKS;
    int b = row >> 9, s = row & (Ss - 1);
    const float* p = preds + (size_t)b * Dd * Ss + s;
    float x0 = p[(size_t)tid * Ss];
    float x1 = p[(size_t)(tid + 256) * Ss];
    __shared__ float red[12];
    float ss = waveReduceSum(x0 * x0 + x1 * x1);
    if (lane == 0) red[wave] = ss;
    __syncthreads();
    float inv = 1.0f / fmaxf(sqrtf(red[0] + red[1] + red[2] + red[3]), 1e-12f);
    float o0 = x0 * inv, o1 = x1 * inv;
    o_rows[(size_t)row * Dd + tid] = o0;
    o_rows[(size_t)row * Dd + tid + 256] = o1;
    int t = target[row];
    const float* et = emb + (size_t)t * Dd;
    float e0 = et[tid], e1 = et[tid + 256];
    u8[(size_t)row * Dd + tid] = f2e4m3(o0 - e0);
    u8[(size_t)row * Dd + tid + 256] = f2e4m3(o1 - e1);
    float ss2 = waveReduceSum(e0 * e0 + e1 * e1);
    float dt = waveReduceSum(o0 * e0 + o1 * e1);
    if (lane == 0) { red[4 + wave] = ss2; red[8 + wave] = dt; }
    __syncthreads();
    if (tid == 0) {
      float n2 = red[4] + red[5] + red[6] + red[7];
      float dd = red[8] + red[9] + red[10] + red[11];
      cos_tgt[row] = dd * (1.0f / fmaxf(sqrtf(n2), 1e-12f));
    }
  }
}

// K2: 128x128-tile MX-fp8 MFMA GEMM (B^T), BK=128 bytes, XOR-8 bank swizzle,
// XCD strips, + coarse per-tile argmax epilogue. Partials row-major.
// One mfma_scale K=128 per (mi,ni) per K-step; uniform scale = 1.0 (E8M0 127).
__global__ __launch_bounds__(256, 3) void gemm_argmax(
    const unsigned char* __restrict__ u8, const unsigned char* __restrict__ e8,
    float* __restrict__ part_s, int* __restrict__ part_i) {
  __shared__ __attribute__((aligned(32))) unsigned char sA[128 * 128];  // 16 KB
  __shared__ __attribute__((aligned(32))) unsigned char sB[128 * 128];  // 16 KB
  int bid = blockIdx.x;
  int g = (bid & 7) * 500 + (bid >> 3);
  int tm = g & 15, tn = g >> 4;
  int tid = threadIdx.x;
  int w = tid >> 6, lane = tid & 63;
  int wm = w >> 1, wn = w & 1;

  // staging: glds dest = wave-base + lane*16 -> row = lane>>3, chunk = lane&7.
  // lane sources GLOBAL 16B chunk (lane&7)^((lane>>3)&7): phys chunk (lane&7)
  // of row r holds logical chunk (lane&7)^(r&7).
  int srow = w * 8 + (lane >> 3);
  int schunk = (lane & 7) ^ ((lane >> 3) & 7);
  const unsigned char* gA = u8 + (size_t)(tm * 128 + srow) * Dd + schunk * 16;
  const unsigned char* gB = e8 + (size_t)(tn * 128 + srow) * Dd + schunk * 16;

  // fragment read (mfma_scale 16x16x128 fp8: row=lane&15, k=(lane>>4)*32+j):
  // lane's 32 logical bytes = logical chunks {2q,2q+1} = phys 32B block at
  // chunk (2q)^(flow&6), halves swapped when flow&1 (same swap for A and B
  // in this lane -> consistent k-permutation -> dot unchanged).
  int fr = lane & 15;
  int q = lane >> 4;
  int flow = fr & 7;
  int foff = (((q << 1) ^ (flow & 6)) << 4);  // 32B-aligned byte offset
  const unsigned char* fA = sA + (size_t)(wm * 64 + fr) * 128 + foff;
  const unsigned char* fB = sB + (size_t)(wn * 64 + fr) * 128 + foff;

  f32x4 acc[4][4];
  f32x4 z = {0.f, 0.f, 0.f, 0.f};
#pragma unroll
  for (int mi = 0; mi < 4; ++mi)
#pragma unroll
    for (int ni = 0; ni < 4; ++ni) acc[mi][ni] = z;

#define MXM(a, b, c) __builtin_amdgcn_mfma_scale_f32_16x16x128_f8f6f4( \
    (a), (b), (c), 0, 0, 0, 0x7F7F7F7F, 0, 0x7F7F7F7F)

  for (int kk = 0; kk < 4; ++kk) {  // 4 K-steps of 128 bytes
    __syncthreads();  // previous compute done before overwrite
    {
      const unsigned char* ga = gA + kk * 128;
      const unsigned char* gb = gB + kk * 128;
#pragma unroll
      for (int i = 0; i < 4; ++i) {
        async_ld16(ga + (size_t)(i * 32) * Dd, &sA[(w * 8 + i * 32) * 128]);
        async_ld16(gb + (size_t)(i * 32) * Dd, &sB[(w * 8 + i * 32) * 128]);
      }
    }
    __syncthreads();  // staging visible (vmcnt drained by barrier)

    // A fragments (row stride 16*128 = 2048 B), 2 rotating B fragments.
    i32x8 af0 = *(const i32x8*)(fA + 0);
    i32x8 af1 = *(const i32x8*)(fA + 2048);
    i32x8 af2 = *(const i32x8*)(fA + 4096);
    i32x8 af3 = *(const i32x8*)(fA + 6144);
    i32x8 b0 = *(const i32x8*)(fB + 0);
    i32x8 b1 = *(const i32x8*)(fB + 2048);
    acc[0][0] = MXM(af0, b0, acc[0][0]);
    acc[1][0] = MXM(af1, b0, acc[1][0]);
    acc[2][0] = MXM(af2, b0, acc[2][0]);
    acc[3][0] = MXM(af3, b0, acc[3][0]);
    b0 = *(const i32x8*)(fB + 4096);
    acc[0][1] = MXM(af0, b1, acc[0][1]);
    acc[1][1] = MXM(af1, b1, acc[1][1]);
    acc[2][1] = MXM(af2, b1, acc[2][1]);
    acc[3][1] = MXM(af3, b1, acc[3][1]);
    b1 = *(const i32x8*)(fB + 6144);
    acc[0][2] = MXM(af0, b0, acc[0][2]);
    acc[1][2] = MXM(af1, b0, acc[1][2]);
    acc[2][2] = MXM(af2, b0, acc[2][2]);
    acc[3][2] = MXM(af3, b0, acc[3][2]);
    acc[0][3] = MXM(af0, b1, acc[0][3]);
    acc[1][3] = MXM(af1, b1, acc[1][3]);
    acc[2][3] = MXM(af2, b1, acc[2][3]);
    acc[3][3] = MXM(af3, b1, acc[3][3]);
  }
#undef MXM

  // ---- coarse argmax epilogue ----
  // C layout: col = lane&15, row = (lane>>4)*4 + reg
  float bs[4][4];
  int bc[4][4];
  int col0 = tn * 128 + wn * 64 + (lane & 15);
#pragma unroll
  for (int mi = 0; mi < 4; ++mi) {
#pragma unroll
    for (int j = 0; j < 4; ++j) { bs[mi][j] = acc[mi][0][j]; bc[mi][j] = col0; }
#pragma unroll
    for (int ni = 1; ni < 4; ++ni) {
      int c = col0 + ni * 16;
#pragma unroll
      for (int j = 0; j < 4; ++j) {
        float v = acc[mi][ni][j];
        if (v > bs[mi][j]) { bs[mi][j] = v; bc[mi][j] = c; }
      }
    }
  }
#pragma unroll
  for (int m = 1; m < 16; m <<= 1) {
#pragma unroll
    for (int mi = 0; mi < 4; ++mi)
#pragma unroll
      for (int j = 0; j < 4; ++j) {
        float os = __shfl_xor(bs[mi][j], m, 64);
        int oc = __shfl_xor(bc[mi][j], m, 64);
        if (os > bs[mi][j] || (os == bs[mi][j] && oc < bc[mi][j])) {
          bs[mi][j] = os;
          bc[mi][j] = oc;
        }
      }
  }
  __syncthreads();  // done reading sA/sB; reuse as merge scratch
  float* sEs = (float*)sA;          // [2][128]
  int* sEc = (int*)sA + 256;        // [2][128]
  if ((lane & 15) == 0) {
    int qq = lane >> 4;
#pragma unroll
    for (int mi = 0; mi < 4; ++mi)
#pragma unroll
      for (int j = 0; j < 4; ++j) {
        int rloc = wm * 64 + mi * 16 + qq * 4 + j;
        sEs[wn * 128 + rloc] = bs[mi][j];
        sEc[wn * 128 + rloc] = bc[mi][j];
      }
  }
  __syncthreads();
  if (tid < 128) {
    float s0 = sEs[tid], s1 = sEs[128 + tid];
    int c0 = sEc[tid], c1 = sEc[128 + tid];
    if (s1 > s0 || (s1 == s0 && c1 < c0)) { s0 = s1; c0 = c1; }
    // row-major partials: coalesced reads in row_final
    part_s[(size_t)(tm * 128 + tid) * 256 + tn] = s0;
    part_i[(size_t)(tm * 128 + tid) * 256 + tn] = c0;
  }
}

// K3: parallel fp32 rescue. One block per row: coalesced partial read,
// block max, LDS candidate list (cols unique per tile), 4 waves rescore
// candidates cooperatively with exact fp32 dots, merge, hinge.
__global__ __launch_bounds__(256) void row_final(
    const float* __restrict__ o_rows, const float* __restrict__ emb,
    const float* __restrict__ inv_norm, const float* __restrict__ cos_tgt,
    const int* __restrict__ target, const int* __restrict__ pad_id,
    const float* __restrict__ part_s, const int* __restrict__ part_i,
    float* __restrict__ diffs) {
  int row = blockIdx.x;
  int tid = threadIdx.x;
  int w = tid >> 6, lane = tid & 63;
  __shared__ float sMax[4];
  __shared__ int sCand[256];
  __shared__ int sCnt;
  __shared__ float sBs[4], sBp[4];
  __shared__ int sBc[4];
  // phase 1: block max over the 250 tile partials (coalesced)
  float v = (tid < NTILE_N) ? part_s[(size_t)row * 256 + tid] : -INFINITY;
  float wmax = waveReduceMax(v);
  if (lane == 0) sMax[w] = wmax;
  if (tid == 0) sCnt = 0;
  __syncthreads();
  float thr = fmaxf(fmaxf(sMax[0], sMax[1]), fmaxf(sMax[2], sMax[3])) - MARGIN;
  // phase 2: candidate list (tile-winner cols are unique across tiles)
  if (tid < NTILE_N && v >= thr) {
    int idx = atomicAdd(&sCnt, 1);
    sCand[idx] = part_i[(size_t)row * 256 + tid];
  }
  __syncthreads();
  int n = sCnt;  // >= 1 (the max tile always qualifies)
  // per-lane row data
  int tgt = target[row];
  const float* o = o_rows + (size_t)row * Dd;
  const float* et = emb + (size_t)tgt * Dd;
  float4 oa = *(const float4*)(o + lane * 8);
  float4 ob = *(const float4*)(o + lane * 8 + 4);
  float4 ta = *(const float4*)(et + lane * 8);
  float4 tb = *(const float4*)(et + lane * 8 + 4);
  // phase 3: waves round-robin candidates
  float bscore = -INFINITY, bpo = 0.f;
  int bcol = 0x7fffffff;
  for (int i = w; i < n; i += 4) {
    int c = sCand[i];
    const float* ec = emb + (size_t)c * Dd;
    float4 ea = *(const float4*)(ec + lane * 8);
    float4 eb = *(const float4*)(ec + lane * 8 + 4);
    float po = oa.x * ea.x + oa.y * ea.y + oa.z * ea.z + oa.w * ea.w +
               ob.x * eb.x + ob.y * eb.y + ob.z * eb.z + ob.w * eb.w;
    float pt = ta.x * ea.x + ta.y * ea.y + ta.z * ea.z + ta.w * ea.w +
               tb.x * eb.x + tb.y * eb.y + tb.z * eb.z + tb.w * eb.w;
    po = waveReduceSum(po);
    pt = waveReduceSum(pt);
    float sc = (po - pt) * inv_norm[c];
    if (sc > bscore || (sc == bscore && c < bcol)) {
      bscore = sc;
      bcol = c;
      bpo = po;
    }
  }
  if (lane == 0) { sBs[w] = bscore; sBc[w] = bcol; sBp[w] = bpo; }
  __syncthreads();
  if (tid == 0) {
    float s = sBs[0], p = sBp[0];
    int c = sBc[0];
#pragma unroll
    for (int i = 1; i < 4; ++i)
      if (sBs[i] > s || (sBs[i] == s && sBc[i] < c)) { s = sBs[i]; c = sBc[i]; p = sBp[i]; }
    float cmax = p * inv_norm[c];
    float df = fmaxf(0.5f + cmax - cos_tgt[row], 0.0f);
    diffs[row] = (tgt != pad_id[0]) ? df : 0.0f;
  }
}

// F: masked mean.
__global__ __launch_bounds__(256) void reduce_final(
    const float* __restrict__ diffs, const int* __restrict__ target,
    const int* __restrict__ pad_id, float* __restrict__ out) {
  int tid = threadIdx.x;
  int pid = pad_id[0];
  float s = 0.f, c = 0.f;
  for (int i = tid; i < ROWS; i += 256) {
    s += diffs[i];
    c += (target[i] != pid) ? 1.0f : 0.0f;
  }
  s = waveReduceSum(s);
  c = waveReduceSum(c);
  __shared__ float rs[4], rc[4];
  int wave = tid >> 6, lane = tid & 63;
  if (lane == 0) { rs[wave] = s; rc[wave] = c; }
  __syncthreads();
  if (tid == 0) out[0] = (rs[0] + rs[1] + rs[2] + rs[3]) / (rc[0] + rc[1] + rc[2] + rc[3]);
}

extern "C" void kernel_launch(void* const* d_in, const int* in_sizes, int n_in,
                              void* d_out, int out_size, void* d_ws, size_t ws_size,
                              hipStream_t stream) {
  const float* preds = (const float*)d_in[0];
  const float* emb = (const float*)d_in[1];
  const int* target = (const int*)d_in[2];
  const int* pad_id = (const int*)d_in[3];
  char* ws = (char*)d_ws;
  // ws layout (bytes), total ~26 MB
  float* o_rows = (float*)ws;                          // 2048*512*4 = 4,194,304
  unsigned char* u8 = (unsigned char*)(ws + 4194304);  // 2048*512   = 1,048,576
  unsigned char* e8 = (unsigned char*)(ws + 5242880);  // 32000*512  = 16,384,000
  float* inv_norm = (float*)(ws + 21626880);           // 32000*4    = 128,000
  float* cos_tgt = (float*)(ws + 21754880);            // 2048*4     = 8,192
  float* part_s = (float*)(ws + 21763072);             // 2048*256*4 = 2,097,152
  int* part_i = (int*)(ws + 23860224);                 // 2048*256*4 = 2,097,152
  float* diffs = (float*)(ws + 25957376);              // 2048*4

  prep_all<<<VOC_BLOCKS + ROWS, 256, 0, stream>>>(preds, emb, target, o_rows, u8,
                                                  cos_tgt, e8, inv_norm);
  gemm_argmax<<<NTILE_M * NTILE_N, 256, 0, stream>>>(u8, e8, part_s, part_i);
  row_final<<<ROWS, 256, 0, stream>>>(o_rows, emb, inv_norm, cos_tgt, target,
                                      pad_id, part_s, part_i, diffs);
  reduce_final<<<1, 256, 0, stream>>>(diffs, target, pad_id, (float*)d_out);
}

// Round 4
// 241.898 us; speedup vs baseline: 1.9477x; 1.5548x over previous
//
#include <hip/hip_runtime.h>
#include <math.h>

// MaxMarginLoss: B=4,S=512,D=512,V=32000, gamma=0.5, eps=1e-12
// score[r,v] = (out_norm[r] - tgt_emb[r]) . voc_norm[v]  -> argmax_v (first-idx ties)
// loss = mean over non-pad rows of max(gamma + cos(out,voc[jmax]) - cos(out,voc[tgt]), 0)
//
// R16 = R15 resubmit (round 3 was an infra failure, not a kernel verdict) +
// single rotating B fragment in the inner loop (frees 8 arch VGPRs).
// Spill model: arch/agpr split of the unified RF. R12 worked (60 arch + 64
// agpr <= 128). MX kernel needs ~80-100 arch; (256,4)/(256,3) gave it 64/84
// -> arch-side spill (1.0-1.5 GB scratch traffic = whole-kernel cost).
// (256,2) -> 256/wave -> arch half ~128 >= demand; single-b drops demand.

#define Bb 4
#define Ss 512
#define Dd 512
#define Vv 32000
#define ROWS (Bb * Ss)          // 2048
#define NTILE_M (ROWS / 128)    // 16
#define NTILE_N (Vv / 128)      // 250
#define VOC_BLOCKS (Vv / 4)     // 8000
#define MARGIN 0.5f

typedef __attribute__((ext_vector_type(4))) float f32x4;
typedef __attribute__((ext_vector_type(8))) int i32x8;

__device__ __forceinline__ float waveReduceSum(float x) {
#pragma unroll
  for (int m = 32; m >= 1; m >>= 1) x += __shfl_xor(x, m, 64);
  return x;
}

__device__ __forceinline__ float waveReduceMax(float x) {
#pragma unroll
  for (int m = 32; m >= 1; m >>= 1) x = fmaxf(x, __shfl_xor(x, m, 64));
  return x;
}

// float -> fp8 e4m3 (OCP on gfx950), low byte of packed convert
__device__ __forceinline__ unsigned char f2e4m3(float f) {
  int p = __builtin_amdgcn_cvt_pk_fp8_f32(f, f, 0, false);
  return (unsigned char)(p & 0xff);
}

__device__ __forceinline__ void async_ld16(const void* g, void* l) {
  __builtin_amdgcn_global_load_lds((const __attribute__((address_space(1))) void*)g,
                                   (__attribute__((address_space(3))) void*)l, 16, 0, 0);
}

// K1: fused prep. blocks [0,8000): 4 vocab rows -> e8 (normalized, fp8) + inv_norm.
//     blocks [8000,10048): ONE preds row -> o_rows(f32), u8(fp8), cos_tgt(f32).
__global__ __launch_bounds__(256) void prep_all(
    const float* __restrict__ preds, const float* __restrict__ emb,
    const int* __restrict__ target,
    float* __restrict__ o_rows, unsigned char* __restrict__ u8,
    float* __restrict__ cos_tgt, unsigned char* __restrict__ e8,
    float* __restrict__ inv_norm) {
  int tid = threadIdx.x;
  int wave = tid >> 6, lane = tid & 63;
  if (blockIdx.x < VOC_BLOCKS) {
    int v = blockIdx.x * 4 + wave;
    const float* e = emb + (size_t)v * Dd;
    float4 x0 = *(const float4*)(e + lane * 8);
    float4 x1 = *(const float4*)(e + lane * 8 + 4);
    float ss = x0.x * x0.x + x0.y * x0.y + x0.z * x0.z + x0.w * x0.w +
               x1.x * x1.x + x1.y * x1.y + x1.z * x1.z + x1.w * x1.w;
    ss = waveReduceSum(ss);
    float inv = 1.0f / fmaxf(sqrtf(ss), 1e-12f);
    int lo = __builtin_amdgcn_cvt_pk_fp8_f32(x0.x * inv, x0.y * inv, 0, false);
    lo = __builtin_amdgcn_cvt_pk_fp8_f32(x0.z * inv, x0.w * inv, lo, true);
    int hi = __builtin_amdgcn_cvt_pk_fp8_f32(x1.x * inv, x1.y * inv, 0, false);
    hi = __builtin_amdgcn_cvt_pk_fp8_f32(x1.z * inv, x1.w * inv, hi, true);
    int2 pk = make_int2(lo, hi);
    *(int2*)(e8 + (size_t)v * Dd + lane * 8) = pk;
    if (lane == 0) inv_norm[v] = inv;
  } else {
    int row = blockIdx.x - VOC_BLOCKS;
    int b = row >> 9, s = row & (Ss - 1);
    const float* p = preds + (size_t)b * Dd * Ss + s;
    float x0 = p[(size_t)tid * Ss];
    float x1 = p[(size_t)(tid + 256) * Ss];
    __shared__ float red[12];
    float ss = waveReduceSum(x0 * x0 + x1 * x1);
    if (lane == 0) red[wave] = ss;
    __syncthreads();
    float inv = 1.0f / fmaxf(sqrtf(red[0] + red[1] + red[2] + red[3]), 1e-12f);
    float o0 = x0 * inv, o1 = x1 * inv;
    o_rows[(size_t)row * Dd + tid] = o0;
    o_rows[(size_t)row * Dd + tid + 256] = o1;
    int t = target[row];
    const float* et = emb + (size_t)t * Dd;
    float e0 = et[tid], e1 = et[tid + 256];
    u8[(size_t)row * Dd + tid] = f2e4m3(o0 - e0);
    u8[(size_t)row * Dd + tid + 256] = f2e4m3(o1 - e1);
    float ss2 = waveReduceSum(e0 * e0 + e1 * e1);
    float dt = waveReduceSum(o0 * e0 + o1 * e1);
    if (lane == 0) { red[4 + wave] = ss2; red[8 + wave] = dt; }
    __syncthreads();
    if (tid == 0) {
      float n2 = red[4] + red[5] + red[6] + red[7];
      float dd = red[8] + red[9] + red[10] + red[11];
      cos_tgt[row] = dd * (1.0f / fmaxf(sqrtf(n2), 1e-12f));
    }
  }
}

// K2: 128x128-tile MX-fp8 MFMA GEMM (B^T), BK=128 bytes, XOR-8 bank swizzle,
// XCD strips, + coarse per-tile argmax epilogue. Partials row-major.
// One mfma_scale K=128 per (mi,ni) per K-step; uniform scale = 1.0 (E8M0 127).
__global__ __launch_bounds__(256, 2) void gemm_argmax(
    const unsigned char* __restrict__ u8, const unsigned char* __restrict__ e8,
    float* __restrict__ part_s, int* __restrict__ part_i) {
  __shared__ __attribute__((aligned(32))) unsigned char sA[128 * 128];  // 16 KB
  __shared__ __attribute__((aligned(32))) unsigned char sB[128 * 128];  // 16 KB
  int bid = blockIdx.x;
  int g = (bid & 7) * 500 + (bid >> 3);
  int tm = g & 15, tn = g >> 4;
  int tid = threadIdx.x;
  int w = tid >> 6, lane = tid & 63;
  int wm = w >> 1, wn = w & 1;

  // staging: glds dest = wave-base + lane*16 -> row = lane>>3, chunk = lane&7.
  // lane sources GLOBAL 16B chunk (lane&7)^((lane>>3)&7): phys chunk (lane&7)
  // of row r holds logical chunk (lane&7)^(r&7).
  int srow = w * 8 + (lane >> 3);
  int schunk = (lane & 7) ^ ((lane >> 3) & 7);
  const unsigned char* gA = u8 + (size_t)(tm * 128 + srow) * Dd + schunk * 16;
  const unsigned char* gB = e8 + (size_t)(tn * 128 + srow) * Dd + schunk * 16;

  // fragment read (mfma_scale 16x16x128 fp8: row=lane&15, k=(lane>>4)*32+j):
  // lane's 32 logical bytes = logical chunks {2q,2q+1} = phys 32B block at
  // chunk (2q)^(flow&6), halves swapped when flow&1 (same swap for A and B
  // in this lane -> consistent k-permutation -> dot unchanged).
  int fr = lane & 15;
  int q = lane >> 4;
  int flow = fr & 7;
  int foff = (((q << 1) ^ (flow & 6)) << 4);  // 32B-aligned byte offset
  const unsigned char* fA = sA + (size_t)(wm * 64 + fr) * 128 + foff;
  const unsigned char* fB = sB + (size_t)(wn * 64 + fr) * 128 + foff;

  f32x4 acc[4][4];
  f32x4 z = {0.f, 0.f, 0.f, 0.f};
#pragma unroll
  for (int mi = 0; mi < 4; ++mi)
#pragma unroll
    for (int ni = 0; ni < 4; ++ni) acc[mi][ni] = z;

#define MXM(a, b, c) __builtin_amdgcn_mfma_scale_f32_16x16x128_f8f6f4( \
    (a), (b), (c), 0, 0, 0, 0x7F7F7F7F, 0, 0x7F7F7F7F)

  for (int kk = 0; kk < 4; ++kk) {  // 4 K-steps of 128 bytes
    __syncthreads();  // previous compute done before overwrite
    {
      const unsigned char* ga = gA + kk * 128;
      const unsigned char* gb = gB + kk * 128;
#pragma unroll
      for (int i = 0; i < 4; ++i) {
        async_ld16(ga + (size_t)(i * 32) * Dd, &sA[(w * 8 + i * 32) * 128]);
        async_ld16(gb + (size_t)(i * 32) * Dd, &sB[(w * 8 + i * 32) * 128]);
      }
    }
    __syncthreads();  // staging visible (vmcnt drained by barrier)

    // A fragments (row stride 16*128 = 2048 B), single rotating B fragment.
    i32x8 af0 = *(const i32x8*)(fA + 0);
    i32x8 af1 = *(const i32x8*)(fA + 2048);
    i32x8 af2 = *(const i32x8*)(fA + 4096);
    i32x8 af3 = *(const i32x8*)(fA + 6144);
#pragma unroll
    for (int ni = 0; ni < 4; ++ni) {
      i32x8 b = *(const i32x8*)(fB + ni * 2048);
      acc[0][ni] = MXM(af0, b, acc[0][ni]);
      acc[1][ni] = MXM(af1, b, acc[1][ni]);
      acc[2][ni] = MXM(af2, b, acc[2][ni]);
      acc[3][ni] = MXM(af3, b, acc[3][ni]);
    }
  }
#undef MXM

  // ---- coarse argmax epilogue ----
  // C layout: col = lane&15, row = (lane>>4)*4 + reg
  float bs[4][4];
  int bc[4][4];
  int col0 = tn * 128 + wn * 64 + (lane & 15);
#pragma unroll
  for (int mi = 0; mi < 4; ++mi) {
#pragma unroll
    for (int j = 0; j < 4; ++j) { bs[mi][j] = acc[mi][0][j]; bc[mi][j] = col0; }
#pragma unroll
    for (int ni = 1; ni < 4; ++ni) {
      int c = col0 + ni * 16;
#pragma unroll
      for (int j = 0; j < 4; ++j) {
        float v = acc[mi][ni][j];
        if (v > bs[mi][j]) { bs[mi][j] = v; bc[mi][j] = c; }
      }
    }
  }
#pragma unroll
  for (int m = 1; m < 16; m <<= 1) {
#pragma unroll
    for (int mi = 0; mi < 4; ++mi)
#pragma unroll
      for (int j = 0; j < 4; ++j) {
        float os = __shfl_xor(bs[mi][j], m, 64);
        int oc = __shfl_xor(bc[mi][j], m, 64);
        if (os > bs[mi][j] || (os == bs[mi][j] && oc < bc[mi][j])) {
          bs[mi][j] = os;
          bc[mi][j] = oc;
        }
      }
  }
  __syncthreads();  // done reading sA/sB; reuse as merge scratch
  float* sEs = (float*)sA;          // [2][128]
  int* sEc = (int*)sA + 256;        // [2][128]
  if ((lane & 15) == 0) {
    int qq = lane >> 4;
#pragma unroll
    for (int mi = 0; mi < 4; ++mi)
#pragma unroll
      for (int j = 0; j < 4; ++j) {
        int rloc = wm * 64 + mi * 16 + qq * 4 + j;
        sEs[wn * 128 + rloc] = bs[mi][j];
        sEc[wn * 128 + rloc] = bc[mi][j];
      }
  }
  __syncthreads();
  if (tid < 128) {
    float s0 = sEs[tid], s1 = sEs[128 + tid];
    int c0 = sEc[tid], c1 = sEc[128 + tid];
    if (s1 > s0 || (s1 == s0 && c1 < c0)) { s0 = s1; c0 = c1; }
    // row-major partials: coalesced reads in row_final
    part_s[(size_t)(tm * 128 + tid) * 256 + tn] = s0;
    part_i[(size_t)(tm * 128 + tid) * 256 + tn] = c0;
  }
}

// K3: parallel fp32 rescue. One block per row: coalesced partial read,
// block max, LDS candidate list (cols unique per tile), 4 waves rescore
// candidates cooperatively with exact fp32 dots, merge, hinge.
__global__ __launch_bounds__(256) void row_final(
    const float* __restrict__ o_rows, const float* __restrict__ emb,
    const float* __restrict__ inv_norm, const float* __restrict__ cos_tgt,
    const int* __restrict__ target, const int* __restrict__ pad_id,
    const float* __restrict__ part_s, const int* __restrict__ part_i,
    float* __restrict__ diffs) {
  int row = blockIdx.x;
  int tid = threadIdx.x;
  int w = tid >> 6, lane = tid & 63;
  __shared__ float sMax[4];
  __shared__ int sCand[256];
  __shared__ int sCnt;
  __shared__ float sBs[4], sBp[4];
  __shared__ int sBc[4];
  // phase 1: block max over the 250 tile partials (coalesced)
  float v = (tid < NTILE_N) ? part_s[(size_t)row * 256 + tid] : -INFINITY;
  float wmax = waveReduceMax(v);
  if (lane == 0) sMax[w] = wmax;
  if (tid == 0) sCnt = 0;
  __syncthreads();
  float thr = fmaxf(fmaxf(sMax[0], sMax[1]), fmaxf(sMax[2], sMax[3])) - MARGIN;
  // phase 2: candidate list (tile-winner cols are unique across tiles)
  if (tid < NTILE_N && v >= thr) {
    int idx = atomicAdd(&sCnt, 1);
    sCand[idx] = part_i[(size_t)row * 256 + tid];
  }
  __syncthreads();
  int n = sCnt;  // >= 1 (the max tile always qualifies)
  // per-lane row data
  int tgt = target[row];
  const float* o = o_rows + (size_t)row * Dd;
  const float* et = emb + (size_t)tgt * Dd;
  float4 oa = *(const float4*)(o + lane * 8);
  float4 ob = *(const float4*)(o + lane * 8 + 4);
  float4 ta = *(const float4*)(et + lane * 8);
  float4 tb = *(const float4*)(et + lane * 8 + 4);
  // phase 3: waves round-robin candidates
  float bscore = -INFINITY, bpo = 0.f;
  int bcol = 0x7fffffff;
  for (int i = w; i < n; i += 4) {
    int c = sCand[i];
    const float* ec = emb + (size_t)c * Dd;
    float4 ea = *(const float4*)(ec + lane * 8);
    float4 eb = *(const float4*)(ec + lane * 8 + 4);
    float po = oa.x * ea.x + oa.y * ea.y + oa.z * ea.z + oa.w * ea.w +
               ob.x * eb.x + ob.y * eb.y + ob.z * eb.z + ob.w * eb.w;
    float pt = ta.x * ea.x + ta.y * ea.y + ta.z * ea.z + ta.w * ea.w +
               tb.x * eb.x + tb.y * eb.y + tb.z * eb.z + tb.w * eb.w;
    po = waveReduceSum(po);
    pt = waveReduceSum(pt);
    float sc = (po - pt) * inv_norm[c];
    if (sc > bscore || (sc == bscore && c < bcol)) {
      bscore = sc;
      bcol = c;
      bpo = po;
    }
  }
  if (lane == 0) { sBs[w] = bscore; sBc[w] = bcol; sBp[w] = bpo; }
  __syncthreads();
  if (tid == 0) {
    float s = sBs[0], p = sBp[0];
    int c = sBc[0];
#pragma unroll
    for (int i = 1; i < 4; ++i)
      if (sBs[i] > s || (sBs[i] == s && sBc[i] < c)) { s = sBs[i]; c = sBc[i]; p = sBp[i]; }
    float cmax = p * inv_norm[c];
    float df = fmaxf(0.5f + cmax - cos_tgt[row], 0.0f);
    diffs[row] = (tgt != pad_id[0]) ? df : 0.0f;
  }
}

// F: masked mean.
__global__ __launch_bounds__(256) void reduce_final(
    const float* __restrict__ diffs, const int* __restrict__ target,
    const int* __restrict__ pad_id, float* __restrict__ out) {
  int tid = threadIdx.x;
  int pid = pad_id[0];
  float s = 0.f, c = 0.f;
  for (int i = tid; i < ROWS; i += 256) {
    s += diffs[i];
    c += (target[i] != pid) ? 1.0f : 0.0f;
  }
  s = waveReduceSum(s);
  c = waveReduceSum(c);
  __shared__ float rs[4], rc[4];
  int wave = tid >> 6, lane = tid & 63;
  if (lane == 0) { rs[wave] = s; rc[wave] = c; }
  __syncthreads();
  if (tid == 0) out[0] = (rs[0] + rs[1] + rs[2] + rs[3]) / (rc[0] + rc[1] + rc[2] + rc[3]);
}

extern "C" void kernel_launch(void* const* d_in, const int* in_sizes, int n_in,
                              void* d_out, int out_size, void* d_ws, size_t ws_size,
                              hipStream_t stream) {
  const float* preds = (const float*)d_in[0];
  const float* emb = (const float*)d_in[1];
  const int* target = (const int*)d_in[2];
  const int* pad_id = (const int*)d_in[3];
  char* ws = (char*)d_ws;
  // ws layout (bytes), total ~26 MB
  float* o_rows = (float*)ws;                          // 2048*512*4 = 4,194,304
  unsigned char* u8 = (unsigned char*)(ws + 4194304);  // 2048*512   = 1,048,576
  unsigned char* e8 = (unsigned char*)(ws + 5242880);  // 32000*512  = 16,384,000
  float* inv_norm = (float*)(ws + 21626880);           // 32000*4    = 128,000
  float* cos_tgt = (float*)(ws + 21754880);            // 2048*4     = 8,192
  float* part_s = (float*)(ws + 21763072);             // 2048*256*4 = 2,097,152
  int* part_i = (int*)(ws + 23860224);                 // 2048*256*4 = 2,097,152
  float* diffs = (float*)(ws + 25957376);              // 2048*4

  prep_all<<<VOC_BLOCKS + ROWS, 256, 0, stream>>>(preds, emb, target, o_rows, u8,
                                                  cos_tgt, e8, inv_norm);
  gemm_argmax<<<NTILE_M * NTILE_N, 256, 0, stream>>>(u8, e8, part_s, part_i);
  row_final<<<ROWS, 256, 0, stream>>>(o_rows, emb, inv_norm, cos_tgt, target,
                                      pad_id, part_s, part_i, diffs);
  reduce_final<<<1, 256, 0, stream>>>(diffs, target, pad_id, (float*)d_out);
}